// Round 12
// baseline (185.061 us; speedup 1.0000x reference)
//
#include <hip/hip_runtime.h>

#define BB 4
#define NN 4096
#define GG 1024
#define CC 32
#define NSIG 4
#define PVALS 132          // 128 agg + 4 dens per (b,g)
#define NT 128             // points per LDS tile
#define KS_PER_TILE (NT / 32)
#define NCHUNK 8
#define NGT (GG / 64)      // g-tiles

// sigma = {0.01, 0.05, 0.1, 0.2} -> k = -0.5/sigma^2 = {-5000, -200, -50, -12.5}
// w(0.1)=w(0.2)^4, w(0.05)=w(0.1)^4 (repeated squaring); exp2 only for 0.2, 0.01.
#define C3 (-18.033688011112042f)   // -12.5/ln2  (sigma=0.2)
#define C0 (-7213.4752044448170f)   // -5000/ln2  (sigma=0.01)

typedef __attribute__((ext_vector_type(8))) short bf16x8;
typedef __attribute__((ext_vector_type(4))) float f32x4;

union frag_u { unsigned u[4]; bf16x8 v; };

__device__ __forceinline__ unsigned pack_bf16(float lo, float hi) {
    unsigned a = __float_as_uint(lo) + 0x8000u;
    unsigned b = __float_as_uint(hi) + 0x8000u;
    return __builtin_amdgcn_perm(b, a, 0x07060302u);
}

#define AS1 __attribute__((address_space(1)))
#define AS3 __attribute__((address_space(3)))
__device__ __forceinline__ void ld_lds16(const void* g, void* l) {
    __builtin_amdgcn_global_load_lds((const AS1 unsigned*)g, (AS3 unsigned*)l, 16, 0, 0);
}
__device__ __forceinline__ void ld_lds4(const void* g, void* l) {
    __builtin_amdgcn_global_load_lds((const AS1 unsigned*)g, (AS3 unsigned*)l, 4, 0, 0);
}

// ---- prep: feat*mask -> bf16 in MFMA-B-frag order; mask -> linear bf16 ----
// frag layout: element (b, n, c) -> row R = b*256 + 2*(n/32) + c/16 (1024 B
// rows), lane = ((n%32)/8)*16 + c%16, word = (n%8)/2, half = n%2.
__global__ __launch_bounds__(256) void gsc_prep_kernel(
    const float* __restrict__ pf, const float* __restrict__ pm,
    unsigned* __restrict__ fragw, unsigned* __restrict__ maskw)
{
    const int gid  = blockIdx.x * 256 + threadIdx.x;
    const int c    = gid & 31;
    const int rest = gid >> 5;
    const int np   = rest & (NN / 2 - 1);
    const int b    = rest >> 11;
    const int nl   = np * 2;
    const size_t ng = (size_t)b * NN + nl;
    const float m0 = pm[ng], m1 = pm[ng + 1];
    const float f0 = pf[ng * CC + c] * m0;
    const float f1 = pf[(ng + 1) * CC + c] * m1;
    const int ks = nl >> 5, qq = (nl >> 3) & 3, j = nl & 7, h = c >> 4;
    fragw[(((size_t)b * (NN / 32) + ks) * 2 + h) * 256 +
          (((qq << 4) | (c & 15)) << 2) + (j >> 1)] = pack_bf16(f0, f1);
    if (c == 0) maskw[ng >> 1] = pack_bf16(m0, m1);
}

struct __align__(16) TileBuf {
    unsigned feat[8 * 256];   // 8 frag rows x 1024 B
    float    x[NT];           // 512 B
    unsigned mask[64];        // 128 bf16
};

// ---- main: block = 4 waves, 64 g's, async double-buffered global_load_lds
// staging (R3-verified); epilogue writes the partial slab, then the LAST
// block per (b, g-tile) (device-scope counter) reduces the 8 L2-warm slabs
// and writes final outputs. No separate reduce kernel.
__global__ __launch_bounds__(256) void gsc_mfma_kernel(
    const float* __restrict__ px, const unsigned* __restrict__ fragw,
    const unsigned* __restrict__ maskw, const float* __restrict__ gx,
    float* __restrict__ partial, int* __restrict__ counters,
    float* __restrict__ out0, float* __restrict__ out1)
{
    __shared__ TileBuf tiles[2];
    __shared__ float sdens[256];
    __shared__ int isLast;

    const int tid = threadIdx.x;
    const int w   = tid >> 6;
    const int l   = tid & 63;
    const int q   = l >> 4;
    const int cl  = l & 15;

    int bid = blockIdx.x;
    const int nc = bid % NCHUNK; bid /= NCHUNK;
    const int gg = bid % NGT;
    const int b  = bid / NGT;
    const int gbase0 = gg * 64;
    const int gbase  = gbase0 + w * 16;

    const float gxv = gx[gbase + cl];

    f32x4 acc[NSIG][2];
    f32x4 dacc[NSIG];
#pragma unroll
    for (int s = 0; s < NSIG; ++s) {
        acc[s][0] = (f32x4){0.f, 0.f, 0.f, 0.f};
        acc[s][1] = (f32x4){0.f, 0.f, 0.f, 0.f};
        dacc[s]   = (f32x4){0.f, 0.f, 0.f, 0.f};
    }

    const int chunk   = NN / NCHUNK;     // 512
    const int n_begin = nc * chunk;
    const int T       = chunk / NT;      // 4

    auto stage = [&](int t, int bufi) {
        TileBuf* tb = &tiles[bufi];
        const int n0 = n_begin + t * NT;
        const char* src = (const char*)fragw +
                          ((size_t)b * 256 + (n0 >> 4) + 2 * w) * 1024 + (size_t)l * 16;
        ld_lds16(src,        &tb->feat[(2 * w) * 256]);
        ld_lds16(src + 1024, &tb->feat[(2 * w + 1) * 256]);
        if (w == 0) {
            const float* xs = px + (size_t)b * NN + n0;
            ld_lds4(xs + l,      &tb->x[0]);
            ld_lds4(xs + 64 + l, &tb->x[64]);
        } else if (w == 1) {
            ld_lds4(maskw + (((size_t)b * NN + n0) >> 1) + l, &tb->mask[0]);
        }
    };

    auto compute = [&](int bufi) {
        TileBuf* tb = &tiles[bufi];
#pragma unroll
        for (int ks = 0; ks < KS_PER_TILE; ++ks) {
            const float4 xa = *(const float4*)&tb->x[ks * 32 + q * 8];
            const float4 xb = *(const float4*)&tb->x[ks * 32 + q * 8 + 4];
            float tt[8];
            float d;
            d = xa.x - gxv; tt[0] = d * d;
            d = xa.y - gxv; tt[1] = d * d;
            d = xa.z - gxv; tt[2] = d * d;
            d = xa.w - gxv; tt[3] = d * d;
            d = xb.x - gxv; tt[4] = d * d;
            d = xb.y - gxv; tt[5] = d * d;
            d = xb.z - gxv; tt[6] = d * d;
            d = xb.w - gxv; tt[7] = d * d;

            frag_u a0, a1, a2, a3;
#pragma unroll
            for (int j = 0; j < 8; j += 2) {
                const float w3a = __builtin_amdgcn_exp2f(tt[j]     * C3);
                const float w3b = __builtin_amdgcn_exp2f(tt[j + 1] * C3);
                float s;
                s = w3a * w3a; const float w2a = s * s;   // ^4 -> sigma 0.1
                s = w3b * w3b; const float w2b = s * s;
                s = w2a * w2a; const float w1a = s * s;   // ^4 -> sigma 0.05
                s = w2b * w2b; const float w1b = s * s;
                const float w0a = __builtin_amdgcn_exp2f(tt[j]     * C0);
                const float w0b = __builtin_amdgcn_exp2f(tt[j + 1] * C0);
                a3.u[j >> 1] = pack_bf16(w3a, w3b);
                a2.u[j >> 1] = pack_bf16(w2a, w2b);
                a1.u[j >> 1] = pack_bf16(w1a, w1b);
                a0.u[j >> 1] = pack_bf16(w0a, w0b);
            }

            const bf16x8 amv = *(const bf16x8*)((const char*)tb->mask + ks * 64 + q * 16);
            const bf16x8 bf0 = *(const bf16x8*)&tb->feat[(ks * 2 + 0) * 256 + l * 4];
            const bf16x8 bf1 = *(const bf16x8*)&tb->feat[(ks * 2 + 1) * 256 + l * 4];

            acc[0][0] = __builtin_amdgcn_mfma_f32_16x16x32_bf16(a0.v, bf0, acc[0][0], 0, 0, 0);
            acc[0][1] = __builtin_amdgcn_mfma_f32_16x16x32_bf16(a0.v, bf1, acc[0][1], 0, 0, 0);
            dacc[0]   = __builtin_amdgcn_mfma_f32_16x16x32_bf16(a0.v, amv, dacc[0], 0, 0, 0);
            acc[1][0] = __builtin_amdgcn_mfma_f32_16x16x32_bf16(a1.v, bf0, acc[1][0], 0, 0, 0);
            acc[1][1] = __builtin_amdgcn_mfma_f32_16x16x32_bf16(a1.v, bf1, acc[1][1], 0, 0, 0);
            dacc[1]   = __builtin_amdgcn_mfma_f32_16x16x32_bf16(a1.v, amv, dacc[1], 0, 0, 0);
            acc[2][0] = __builtin_amdgcn_mfma_f32_16x16x32_bf16(a2.v, bf0, acc[2][0], 0, 0, 0);
            acc[2][1] = __builtin_amdgcn_mfma_f32_16x16x32_bf16(a2.v, bf1, acc[2][1], 0, 0, 0);
            dacc[2]   = __builtin_amdgcn_mfma_f32_16x16x32_bf16(a2.v, amv, dacc[2], 0, 0, 0);
            acc[3][0] = __builtin_amdgcn_mfma_f32_16x16x32_bf16(a3.v, bf0, acc[3][0], 0, 0, 0);
            acc[3][1] = __builtin_amdgcn_mfma_f32_16x16x32_bf16(a3.v, bf1, acc[3][1], 0, 0, 0);
            dacc[3]   = __builtin_amdgcn_mfma_f32_16x16x32_bf16(a3.v, amv, dacc[3], 0, 0, 0);
        }
    };

    stage(0, 0);
#pragma unroll 1
    for (int t = 0; t < T; ++t) {
        __syncthreads();                           // drains tile t's loads
        if (t + 1 < T) stage(t + 1, (t + 1) & 1);  // fly during compute(t)
        compute(t & 1);
    }

    // ---- epilogue 1: partial slab write. C/D: col=lane&15 (+16h), row=q*4+r
    float* p = partial + ((size_t)nc * BB * GG + (size_t)b * GG + gbase) * PVALS;
#pragma unroll
    for (int s = 0; s < NSIG; ++s)
#pragma unroll
        for (int h = 0; h < 2; ++h)
#pragma unroll
            for (int r = 0; r < 4; ++r)
                p[(q * 4 + r) * PVALS + s * 32 + h * 16 + cl] = acc[s][h][r];
    if (cl == 0) {
#pragma unroll
        for (int s = 0; s < NSIG; ++s)
#pragma unroll
            for (int r = 0; r < 4; ++r)
                p[(q * 4 + r) * PVALS + 128 + s] = dacc[s][r];
    }

    // ---- epilogue 2: last block per (b, g-tile) reduces the 8 slabs ----
    __threadfence();   // make slab visible device-wide before the count
    if (tid == 0)
        isLast = (atomicAdd(&counters[b * NGT + gg], 1) == NCHUNK - 1);
    __syncthreads();
    if (!isLast) return;
    __threadfence();   // acquire: other blocks' slabs now visible

    // dens first: thread -> (g-local = tid>>2, s = tid&3)
    {
        const int gl2 = tid >> 2, s = tid & 3;
        const size_t row = (size_t)b * GG + gbase0 + gl2;
        float dsum = 0.0f;
#pragma unroll
        for (int nc2 = 0; nc2 < NCHUNK; ++nc2)
            dsum += partial[((size_t)nc2 * BB * GG + row) * PVALS + 128 + s];
        sdens[tid] = dsum;
        out1[row * NSIG + s] = dsum;
    }
    __syncthreads();

    // agg: 64 g x 128 v, 32 values per thread
    for (int idx = tid; idx < 64 * 128; idx += 256) {
        const int gl3 = idx >> 7, v = idx & 127;
        const size_t row = (size_t)b * GG + gbase0 + gl3;
        float sum = 0.0f;
#pragma unroll
        for (int nc2 = 0; nc2 < NCHUNK; ++nc2)
            sum += partial[((size_t)nc2 * BB * GG + row) * PVALS + v];
        out0[row * 128 + v] = sum / fmaxf(sdens[gl3 * 4 + (v >> 5)], 1e-6f);
    }
}

extern "C" void kernel_launch(void* const* d_in, const int* in_sizes, int n_in,
                              void* d_out, int out_size, void* d_ws, size_t ws_size,
                              hipStream_t stream) {
    const float* px = (const float*)d_in[0];  // [B,N]
    const float* pf = (const float*)d_in[1];  // [B,N,C]
    const float* pm = (const float*)d_in[2];  // [B,N]
    const float* gx = (const float*)d_in[3];  // [G]
    float* out0 = (float*)d_out;                          // [B,G,4*C]
    float* out1 = out0 + (size_t)BB * GG * NSIG * CC;     // [B,G,4]

    const size_t fragWords = (size_t)BB * 256 * 256;   // 1 MB
    const size_t maskWords = (size_t)BB * NN / 2;      // 32 KB
    unsigned* fragw = (unsigned*)d_ws;
    unsigned* maskw = fragw + fragWords;
    float* partial  = (float*)(maskw + maskWords);     // 17.3 MB
    int* counters   = (int*)(partial + (size_t)NCHUNK * BB * GG * PVALS);

    hipMemsetAsync(counters, 0, (size_t)BB * NGT * sizeof(int), stream);
    gsc_prep_kernel<<<dim3(BB * (NN / 2) * CC / 256), dim3(256), 0, stream>>>(
        pf, pm, fragw, maskw);
    gsc_mfma_kernel<<<dim3(BB * NGT * NCHUNK), dim3(256), 0, stream>>>(
        px, fragw, maskw, gx, partial, counters, out0, out1);
}